// Round 1
// 476.388 us; speedup vs baseline: 1.0471x; 1.0471x over previous
//
#include <hip/hip_runtime.h>
#include <math.h>

// ---- problem dims ----
#define BB   16
#define SS   8
#define TKK  400
#define HH   256
#define EE   128
#define VV   50000
#define OOVV 50
#define HH2  512
#define STK  (SS*TKK)     // 3200
#define VOO  (VV+OOVV)    // 50050

// ---- workspace offsets (floats) ----
#define OFF_X     0        // B*E      = 2048
#define OFF_ST    2048     // B*H2     = 8192   s_t_hat = [h,c]
#define OFF_SD    10240    // B*H2     = 8192
#define OFF_WD    18432    // B*H2     = 8192
#define OFF_SCSEC 26752    // B*S      = 128 (plain stores from esec branch)
#define OFF_SCW   26880    // B*S*TK   = 51200 (plain stores from gemm)
#define OFF_CT    78080    // B*H2     = 8192  (zeroed in k_pre, atomic accum)
#define OFF_OUT1  86272    // B*H      = 4096
#define OFF_PGEN  90368    // B        = 16
#define OFF_PSUM  93520    // 16*782   = 12512, layout [b][blk] (plain stores)
#define OFF_BT    113040   // 512*512 bf16 (512KB), layout [round][col*4 + swz(kg)][8]

// ---- output offsets (floats) ----
#define O_FD   0
#define O_H    800800
#define O_C    804896
#define O_CT   808992
#define O_ATTN 817184
#define O_PGEN 868384
#define O_COV  868400

#define NLBLK 782          // logits blocks (64 cols each)
#define GEMM_NB 800

typedef __attribute__((ext_vector_type(8))) short bf16x8;
typedef __attribute__((ext_vector_type(4))) float f32x4;

__device__ __forceinline__ float sigm(float x){ return 1.0f/(1.0f+expf(-x)); }

__device__ __forceinline__ unsigned short f2b(float f){
  unsigned int u = __float_as_uint(f);
  unsigned int r = (u + 0x7fffu + ((u >> 16) & 1u)) >> 16;
  return (unsigned short)r;
}

__device__ __forceinline__ float wave_sum(float v){
  #pragma unroll
  for(int o=32;o>0;o>>=1) v += __shfl_xor(v,o);
  return v;
}
__device__ __forceinline__ float wave_max(float v){
  #pragma unroll
  for(int o=32;o>0;o>>=1) v = fmaxf(v,__shfl_xor(v,o));
  return v;
}

// async global->LDS, 16B per lane. LDS dest = wave-uniform base + lane*16.
__device__ __forceinline__ void glds16(const void* g, void* l){
  __builtin_amdgcn_global_load_lds((const __attribute__((address_space(1))) void*)g,
                                   (__attribute__((address_space(3))) void*)l, 16, 0, 0);
}

// ------------------------------------------------------------------
// k_pre: blocks 0..63  transpose Whw -> Btg bf16.
//        Btg layout: [round 0..15][(col*4 + (kg ^ ((col>>1)&3)))*8 + j]
//        where k = round*32 + kg*8 + j. This is exactly the (pre-swizzled)
//        per-round LDS image k_gemm6 copies with global_load_lds.
//        blocks 64..79 x = [c_t_1, emb[y]] @ W_xc + b_xc (8 cols/block, ksplit 2)
//        block  80     zero CT
// grid 81 x 256
__global__ void k_pre(const float* __restrict__ Whw, unsigned short* __restrict__ Btg,
                      const int* __restrict__ y, const float* __restrict__ ct1,
                      const float* __restrict__ emb, const float* __restrict__ Wxc,
                      const float* __restrict__ bxc, float* __restrict__ ws){
  __shared__ float sm[10440];
  int bi = blockIdx.x, tid = threadIdx.x;
  if(bi < 64){
    // load 64x64 tile of Whw [k][n] into LDS (pad 65)
    int n0 = (bi & 7)*64, k0 = (bi >> 3)*64;
    int tx = tid & 63, ty = tid >> 6;  // ty 0..3
    #pragma unroll
    for(int it=0; it<16; it++){
      int kk = it*4 + ty;
      sm[kk*65 + tx] = Whw[(size_t)(k0+kk)*HH2 + n0 + tx];
    }
    __syncthreads();
    #pragma unroll
    for(int it=0; it<2; it++){
      int kgl = it*4 + ty;            // 0..7
      int kgG = (k0 >> 3) + kgl;
      int rnd = kgG >> 2, kg = kgG & 3;
      int col = n0 + tx;
      union{ bf16x8 v; unsigned short u[8]; } t;
      #pragma unroll
      for(int j=0;j<8;j++) t.u[j] = f2b(sm[(kgl*8+j)*65 + tx]);
      *(bf16x8*)&Btg[(size_t)rnd*16384 + (size_t)(col*4 + (kg ^ ((col>>1)&3)))*8] = t.v;
    }
  } else if(bi < 80){
    // x projection: 8 cols per block, k split 2
    float* cat = sm;                  // [b][640]
    float* red = sm + 10240;          // 128
    for(int f=tid; f<BB*640; f+=256){
      int b = f/640, r = f - b*640;
      cat[f] = (r < HH2) ? ct1[b*HH2 + r] : emb[(size_t)y[b]*EE + (r-HH2)];
    }
    __syncthreads();
    int c = (bi-64)*8 + (tid & 7);
    int b = (tid >> 3) & 15;
    int kh = tid >> 7;                // 0..1
    float acc = 0.0f;
    const float* a = &cat[b*640];
    for(int k=kh*320; k<kh*320+320; k++) acc += a[k]*Wxc[k*EE + c];
    if(kh==1) red[b*8 + (tid&7)] = acc;
    __syncthreads();
    if(kh==0) ws[OFF_X + b*EE + c] = acc + red[b*8 + (tid&7)] + bxc[c];
  } else {
    for(int f=tid; f<BB*HH2; f+=256) ws[OFF_CT + f] = 0.0f;
  }
}

// ------------------------------------------------------------------
// fused LSTM.  grid 64 x 256: block = 16 j-cols x 4 b, ksplit 4
__global__ void k_lstm(const float* __restrict__ h0, const float* __restrict__ c0,
                       const float* __restrict__ Wih, const float* __restrict__ bih,
                       const float* __restrict__ Whh, const float* __restrict__ bhh,
                       float* __restrict__ ws, float* __restrict__ out){
  __shared__ float xh[4*384];        // 6 KB  [bl][ x(128) | h0(256) ]
  __shared__ float red[3*64*4];      // 3 KB
  int tid = threadIdx.x;
  int jc = (blockIdx.x & 15)*16, bc = (blockIdx.x >> 4)*4;
  for(int f=tid; f<4*384; f+=256){
    int bl = f/384, r = f - bl*384;
    xh[f] = (r < EE) ? ws[OFF_X + (bc+bl)*EE + r] : h0[(bc+bl)*HH + (r-EE)];
  }
  __syncthreads();
  int jl = tid & 15, bl = (tid >> 4) & 3, kq = tid >> 6;
  int j = jc + jl, b = bc + bl;
  float a0=0.f, a1=0.f, a2=0.f, a3=0.f;
  const float* a = &xh[bl*384];
  for(int k=kq*96; k<kq*96+96; k++){
    float v = a[k];
    const float* w = (k < EE) ? &Wih[k*4*HH + j] : &Whh[(k-EE)*4*HH + j];
    a0 += v*w[0]; a1 += v*w[HH]; a2 += v*w[2*HH]; a3 += v*w[3*HH];
  }
  if(kq){
    float* r = &red[((kq-1)*64 + bl*16 + jl)*4];
    r[0]=a0; r[1]=a1; r[2]=a2; r[3]=a3;
  }
  __syncthreads();
  if(kq==0){
    #pragma unroll
    for(int p=0;p<3;p++){
      const float* r = &red[(p*64 + bl*16 + jl)*4];
      a0+=r[0]; a1+=r[1]; a2+=r[2]; a3+=r[3];
    }
    a0 += bih[j] + bhh[j];
    a1 += bih[j+HH] + bhh[j+HH];
    a2 += bih[j+2*HH] + bhh[j+2*HH];
    a3 += bih[j+3*HH] + bhh[j+3*HH];
    float c = sigm(a1)*c0[b*HH+j] + sigm(a0)*tanhf(a2);
    float h = sigm(a3)*tanhf(c);
    out[O_H + b*HH + j] = h;
    out[O_C + b*HH + j] = c;
    ws[OFF_ST + b*HH2 + j]      = h;
    ws[OFF_ST + b*HH2 + HH + j] = c;
  }
}

// ------------------------------------------------------------------
// sd/wd projections.  grid 128 x 256: blocks 0-63 SD, 64-127 WD.
// block = 8 cols x 16 b, ksplit 2.
__global__ void k_proj(const float* __restrict__ Wdsec, const float* __restrict__ bdsec,
                       const float* __restrict__ Wdw,  const float* __restrict__ bdw,
                       float* __restrict__ ws){
  __shared__ float st[BB*HH2];   // 32 KB
  __shared__ float red[128];
  int tid = threadIdx.x;
  for(int f=tid; f<BB*HH2; f+=256) st[f] = ws[OFF_ST + f];
  __syncthreads();
  int mi = blockIdx.x >> 6;
  int c = (blockIdx.x & 63)*8 + (tid & 7);
  int bl = (tid >> 3) & 15;
  int kq = tid >> 7;   // 0..1
  const float* Wm = mi ? Wdw : Wdsec;
  const float* bias = mi ? bdw : bdsec;
  int dst = mi ? OFF_WD : OFF_SD;
  float acc = 0.0f;
  const float* a = &st[bl*HH2];
  for(int k=kq*256; k<kq*256+256; k++) acc += a[k]*Wm[k*HH2 + c];
  if(kq==1) red[bl*8 + (tid&7)] = acc;
  __syncthreads();
  if(kq==0) ws[dst + bl*HH2 + c] = acc + red[bl*8 + (tid&7)] + bias[c];
}

// ------------------------------------------------------------------
// k_gemm6 blocks 0..799: 64 rows x 512 cols, K=512, BK=32.
//   2-phase pipeline: double-buffered LDS (72KB), one barrier/round.
//   B prefetched via global_load_lds (Btg pre-swizzled by k_pre);
//   A prefetched to regs early, f2b+ds_write after MFMA (T14 split).
//   8 waves as 2 row-groups x 4 col-groups (wave tile 32x128):
//   10 ds_read_b128 + 16 MFMA per wave-round.
//   sc_w[row] = sum_n tanh(enc[row,:]@Whw[:,n] + wd[b,n] + cov[row]*Wcw[n]) * vw[n]
// blocks 800..927: section attention -> plain store SCSEC.
// grid 928 x 512, 72 KB static LDS -> 2 blocks/CU (16 waves).
__global__ __launch_bounds__(512, 4) void k_gemm6(
        const float* __restrict__ A, const unsigned short* __restrict__ Btg,
        const float* __restrict__ Wcw, const float* __restrict__ vw,
        const float* __restrict__ cover,
        const float* __restrict__ sec, const float* __restrict__ Whsec,
        const float* __restrict__ vsec, float* __restrict__ ws){
  // shorts: As0[0..2047] As1[2048..4095] Bs0[4096..20479] Bs1[20480..36863]
  __shared__ __align__(16) unsigned short smem[36864];   // 72 KB
  int tid = threadIdx.x;
  if(blockIdx.x >= GEMM_NB){
    // ---- esec: one block per (b,s) row ----
    float* row = (float*)smem;            // 512 floats
    float* red = row + HH2;               // 8
    int bi = blockIdx.x - GEMM_NB;        // 0..127
    int b = bi >> 3;
    if(tid < HH2) row[tid] = sec[(size_t)bi*HH2 + tid];
    __syncthreads();
    int col = tid;                        // 0..511
    float acc = 0.0f;
    #pragma unroll 8
    for(int k=0;k<HH2;k++) acc += row[k]*Whsec[k*HH2 + col];
    float val = tanhf(acc + ws[OFF_SD + b*HH2 + col]) * vsec[col];
    val = wave_sum(val);
    if((tid&63)==0) red[tid>>6] = val;
    __syncthreads();
    if(tid==0){
      float s = 0.0f;
      #pragma unroll
      for(int i=0;i<8;i++) s += red[i];
      ws[OFF_SCSEC + bi] = s;
    }
    return;
  }
  // ---- gemm ----
  int w = tid >> 6, lane = tid & 63, m = lane & 15, q = lane >> 4;
  int mk = (m >> 1) & 3, sw = q ^ mk;    // XOR-swizzle slot for kg=q reads
  int rg = w >> 2, cg = w & 3;           // 2 row-groups x 4 col-groups
  int row0 = blockIdx.x * 64;
  int b = blockIdx.x / 50;               // 50 blocks per batch (64*50 = 3200)
  int arow = tid >> 2, akg = tid & 3;    // A staging (tid<256): 64 rows x 4 kg
  int adst = (arow*4 + (akg ^ ((arow>>1)&3)))*8;

  f32x4 acc0[8], acc1[8];
  #pragma unroll
  for(int j=0;j<8;j++){ acc0[j] = (f32x4){0.f,0.f,0.f,0.f}; acc1[j] = (f32x4){0.f,0.f,0.f,0.f}; }

  // ---- prologue: stage round 0 into buffer 0 ----
  if(tid < 256){
    const float4* src = (const float4*)&A[(size_t)(row0+arow)*HH2 + akg*8];
    float4 v0 = src[0], v1 = src[1];
    union{ bf16x8 v; unsigned short u[8]; } t;
    t.u[0]=f2b(v0.x); t.u[1]=f2b(v0.y); t.u[2]=f2b(v0.z); t.u[3]=f2b(v0.w);
    t.u[4]=f2b(v1.x); t.u[5]=f2b(v1.y); t.u[6]=f2b(v1.z); t.u[7]=f2b(v1.w);
    *(bf16x8*)&smem[adst] = t.v;
  }
  #pragma unroll
  for(int i=0;i<4;i++)
    glds16(Btg + i*4096 + tid*8, &smem[4096 + i*4096 + tid*8]);
  __syncthreads();

  int a_r0 = (rg*32 + m)*32 + sw*8;        // As short-offset, mi=0
  int a_r1 = (rg*32 + 16 + m)*32 + sw*8;   // mi=1

  #pragma unroll 2
  for(int r=0;r<16;r++){
    int cur = r & 1, nxt = cur ^ 1;
    float4 v0, v1;
    if(r < 15){
      // issue prefetch for round r+1 (A first so its vmcnt wait keeps B in flight)
      if(tid < 256){
        const float4* src = (const float4*)&A[(size_t)(row0+arow)*HH2 + (r+1)*32 + akg*8];
        v0 = src[0]; v1 = src[1];
      }
      const unsigned short* bsrc = Btg + (size_t)(r+1)*16384;
      #pragma unroll
      for(int i=0;i<4;i++)
        glds16(bsrc + i*4096 + tid*8, &smem[4096 + nxt*16384 + i*4096 + tid*8]);
    }
    // compute round r
    int abase = cur*2048, bbase = 4096 + cur*16384;
    bf16x8 af0 = *(const bf16x8*)&smem[abase + a_r0];
    bf16x8 af1 = *(const bf16x8*)&smem[abase + a_r1];
    #pragma unroll
    for(int j=0;j<8;j++){
      int col = cg*128 + j*16 + m;
      bf16x8 bfv = *(const bf16x8*)&smem[bbase + (col*4 + sw)*8];
      acc0[j] = __builtin_amdgcn_mfma_f32_16x16x32_bf16(af0, bfv, acc0[j], 0,0,0);
      acc1[j] = __builtin_amdgcn_mfma_f32_16x16x32_bf16(af1, bfv, acc1[j], 0,0,0);
    }
    // late write of the A prefetch (vmcnt wait lands here, after MFMA)
    if(r < 15 && tid < 256){
      union{ bf16x8 v; unsigned short u[8]; } t;
      t.u[0]=f2b(v0.x); t.u[1]=f2b(v0.y); t.u[2]=f2b(v0.z); t.u[3]=f2b(v0.w);
      t.u[4]=f2b(v1.x); t.u[5]=f2b(v1.y); t.u[6]=f2b(v1.z); t.u[7]=f2b(v1.w);
      *(bf16x8*)&smem[nxt*2048 + adst] = t.v;
    }
    __syncthreads();
  }

  // ---- epilogue: fold cols with tanh into per-row sums ----
  float cov0[4], cov1[4];
  #pragma unroll
  for(int r=0;r<4;r++){
    cov0[r] = cover[row0 + rg*32 + q*4 + r];
    cov1[r] = cover[row0 + rg*32 + 16 + q*4 + r];
  }
  float rs0[4] = {0,0,0,0}, rs1[4] = {0,0,0,0};
  #pragma unroll
  for(int j=0;j<8;j++){
    int col = cg*128 + j*16 + m;
    float wdv = ws[OFF_WD + b*HH2 + col];
    float wcv = Wcw[col], vwv = vw[col];
    #pragma unroll
    for(int r=0;r<4;r++){
      rs0[r] += tanhf(acc0[j][r] + wdv + cov0[r]*wcv) * vwv;
      rs1[r] += tanhf(acc1[j][r] + wdv + cov1[r]*wcv) * vwv;
    }
  }
  float* rbuf = (float*)smem;   // 256 floats; safe after final barrier
  #pragma unroll
  for(int r=0;r<4;r++){
    float v = rs0[r];
    v += __shfl_xor(v,1,16); v += __shfl_xor(v,2,16);
    v += __shfl_xor(v,4,16); v += __shfl_xor(v,8,16);
    if(m==0) rbuf[cg*64 + rg*32 + q*4 + r] = v;
    float u = rs1[r];
    u += __shfl_xor(u,1,16); u += __shfl_xor(u,2,16);
    u += __shfl_xor(u,4,16); u += __shfl_xor(u,8,16);
    if(m==0) rbuf[cg*64 + rg*32 + 16 + q*4 + r] = u;
  }
  __syncthreads();
  if(tid < 64)
    ws[OFF_SCW + row0 + tid] = rbuf[tid] + rbuf[64+tid] + rbuf[128+tid] + rbuf[192+tid];
}

// ------------------------------------------------------------------
// beta (inline) + attn softmax + mask + renorm + coverage out.  grid 16 x 256
__global__ void k_attn(const float* __restrict__ mask, const float* __restrict__ cover,
                       float* __restrict__ ws, float* __restrict__ out){
  int b = blockIdx.x, tid = threadIdx.x;
  __shared__ float vals[STK];
  __shared__ float red[4];
  __shared__ float sc[SS];
  if(tid < SS) sc[tid] = ws[OFF_SCSEC + b*SS + tid];
  __syncthreads();
  float bm = -1e30f;
  #pragma unroll
  for(int s=0;s<SS;s++) bm = fmaxf(bm, sc[s]);
  float be[SS]; float bsum = 0.0f;
  #pragma unroll
  for(int s=0;s<SS;s++){ be[s] = expf(sc[s]-bm); bsum += be[s]; }
  #pragma unroll
  for(int s=0;s<SS;s++) be[s] /= bsum;
  int lane = tid & 63, w = tid >> 6;
  float m = -1e30f;
  for(int j=tid;j<STK;j+=256){
    float v = be[j/TKK] * ws[OFF_SCW + b*STK + j];
    vals[j] = v; m = fmaxf(m, v);
  }
  m = wave_max(m);
  if(lane==0) red[w] = m;
  __syncthreads();
  m = fmaxf(fmaxf(red[0],red[1]), fmaxf(red[2],red[3]));
  __syncthreads();
  float ssum = 0.0f;
  for(int j=tid;j<STK;j+=256){
    float e = expf(vals[j]-m) * mask[b*STK + j];
    vals[j] = e; ssum += e;
  }
  ssum = wave_sum(ssum);
  if(lane==0) red[w] = ssum;
  __syncthreads();
  float inv = 1.0f/(red[0]+red[1]+red[2]+red[3]);
  for(int j=tid;j<STK;j+=256){
    float a = vals[j]*inv;
    out[O_ATTN + b*STK + j] = a;
    out[O_COV  + b*STK + j] = cover[b*STK + j] + a;
  }
}

// ------------------------------------------------------------------
// c_t = attn @ enc.  grid (50,16) x 256, atomic accumulate into CT
__global__ void k_ct(const float* __restrict__ enc, const float* __restrict__ out,
                     float* __restrict__ ws){
  int b = blockIdx.y, tid = threadIdx.x;
  __shared__ float a[64];
  int t0 = blockIdx.x*64;
  if(tid<64) a[tid] = out[O_ATTN + b*STK + t0 + tid];
  __syncthreads();
  float acc0=0.0f, acc1=0.0f;
  #pragma unroll 4
  for(int tt=0;tt<64;tt++){
    const float* row = &enc[(size_t)(b*STK + t0 + tt)*HH2];
    float av = a[tt];
    acc0 += av*row[tid];
    acc1 += av*row[256+tid];
  }
  atomicAdd(&ws[OFF_CT + b*HH2 + tid],       acc0);
  atomicAdd(&ws[OFF_CT + b*HH2 + 256 + tid], acc1);
}

// ------------------------------------------------------------------
// out1: grid 65 x 256. blocks 0..63: 4 cols x 16 b, ksplit 4.
// block 64: p_gen (4 waves x 4 b each) + c_t output copy.
__global__ void k_out1(const float* __restrict__ Wp, const float* __restrict__ bp,
                       const float* __restrict__ Wo1, const float* __restrict__ bo1,
                       float* __restrict__ ws, float* __restrict__ out){
  __shared__ float cat[BB*768];   // 48 KB  [b][ h(256) | ct(512) ]
  __shared__ float red[3*64];
  int tid = threadIdx.x;
  if(blockIdx.x == 64){
    int w = tid >> 6, lane = tid & 63;
    #pragma unroll
    for(int i=0;i<4;i++){
      int b = w*4 + i;
      float p = 0.0f;
      for(int k=lane;k<4*HH+EE;k+=64){
        float val = (k < HH2) ? ws[OFF_CT + b*HH2 + k]
                  : (k < 4*HH) ? ws[OFF_ST + b*HH2 + (k-HH2)]
                  : ws[OFF_X + b*EE + (k-4*HH)];
        p += val * Wp[k];
      }
      p = wave_sum(p);
      if(lane==0){
        float pg = sigm(p + bp[0]);
        ws[OFF_PGEN + b] = pg;
        out[O_PGEN + b]  = pg;
      }
    }
    for(int f=tid; f<BB*HH2; f+=256) out[O_CT + f] = ws[OFF_CT + f];
    return;
  }
  for(int f=tid; f<BB*768; f+=256){
    int b = f/768, r = f - b*768;
    cat[f] = (r < HH) ? ws[OFF_ST + b*HH2 + r] : ws[OFF_CT + b*HH2 + (r-HH)];
  }
  __syncthreads();
  int cl = tid & 3, bl = (tid >> 2) & 15, kq = tid >> 6;
  int c = blockIdx.x*4 + cl;
  float acc = 0.0f;
  const float* a = &cat[bl*768];
  for(int k=kq*192; k<kq*192+192; k++) acc += a[k]*Wo1[k*HH + c];
  if(kq) red[(kq-1)*64 + bl*4 + cl] = acc;
  __syncthreads();
  if(kq==0){
    acc += red[bl*4+cl] + red[64 + bl*4+cl] + red[128 + bl*4+cl];
    ws[OFF_OUT1 + bl*HH + c] = acc + bo1[c];
  }
}

// ------------------------------------------------------------------
// logits -> exp (logits tiny, no max needed) + per-block PSUM.  grid 782 x 256
// PSUM layout [b][blk] so k_final reads are coalesced.
__global__ void k_logits(const float* __restrict__ W2, const float* __restrict__ b2,
                         float* __restrict__ ws, float* __restrict__ out){
  int tid = threadIdx.x;
  int c = blockIdx.x*64 + (tid & 63);
  int bq = tid >> 6;                 // 0..3 -> b = bq*4..bq*4+3
  __shared__ float o1[BB*HH];        // 16 KB
  for(int i=tid;i<BB*HH;i+=256) o1[i] = ws[OFF_OUT1 + i];
  __syncthreads();
  bool ok = c < VV;
  float acc[4] = {0,0,0,0};
  if(ok){
    for(int k=0;k<HH;k++){
      float wv = W2[(size_t)k*VV + c];
      #pragma unroll
      for(int i=0;i<4;i++) acc[i] += o1[(bq*4+i)*HH + k]*wv;
    }
  }
  float bias = ok ? b2[c] : 0.0f;
  int lane = tid & 63;
  #pragma unroll
  for(int i=0;i<4;i++){
    float e = ok ? expf(acc[i]+bias) : 0.0f;
    if(ok) out[(size_t)(bq*4+i)*VOO + c] = e;
    float sv = wave_sum(e);
    if(lane==0) ws[OFF_PSUM + (bq*4+i)*NLBLK + blockIdx.x] = sv;
  }
}

// ------------------------------------------------------------------
// final_dist = p_gen * e / sum (v<V), extra_zeros tail.  grid (196,16) x 256
__global__ void k_final(const float* __restrict__ xz, float* __restrict__ ws,
                        float* __restrict__ out){
  int b = blockIdx.y;
  int v = blockIdx.x*256 + threadIdx.x;
  __shared__ float red[4];
  int lane = threadIdx.x & 63, w = threadIdx.x >> 6;
  float p = 0.0f;
  for(int i=threadIdx.x;i<NLBLK;i+=256) p += ws[OFF_PSUM + b*NLBLK + i];
  p = wave_sum(p);
  if(lane==0) red[w] = p;
  __syncthreads();
  float s = red[0]+red[1]+red[2]+red[3];
  float pg = ws[OFF_PGEN + b];
  if(v < VV)       out[(size_t)b*VOO + v] = pg * out[(size_t)b*VOO + v] / s;
  else if(v < VOO) out[(size_t)b*VOO + v] = xz[b*OOVV + (v-VV)];
}

// ------------------------------------------------------------------
// scatter-add (1-p_gen)*attn at extend-vocab indices.  grid 16 x 256
__global__ void k_scatter(const int* __restrict__ ebev, float* __restrict__ ws,
                          float* __restrict__ out){
  int b = blockIdx.x;
  float r = 1.0f - ws[OFF_PGEN + b];
  for(int j=threadIdx.x;j<STK;j+=256){
    int idx = ebev[b*STK + j];
    atomicAdd(&out[(size_t)b*VOO + idx], r*out[O_ATTN + b*STK + j]);
  }
}

extern "C" void kernel_launch(void* const* d_in, const int* in_sizes, int n_in,
                              void* d_out, int out_size, void* d_ws, size_t ws_size,
                              hipStream_t stream){
  const int*   y     = (const int*)  d_in[0];
  const float* h0    = (const float*)d_in[1];
  const float* c0    = (const float*)d_in[2];
  const float* enc   = (const float*)d_in[3];
  const float* sec   = (const float*)d_in[4];
  const float* mask  = (const float*)d_in[5];
  const float* ct1   = (const float*)d_in[6];
  const float* xz    = (const float*)d_in[7];
  const int*   ebev  = (const int*)  d_in[8];
  const float* cover = (const float*)d_in[9];
  /* d_in[10] = gamma (unused by reference) */
  const float* emb   = (const float*)d_in[11];
  const float* Wxc   = (const float*)d_in[12];
  const float* bxc   = (const float*)d_in[13];
  const float* Wih   = (const float*)d_in[14];
  const float* bih   = (const float*)d_in[15];
  const float* Whh   = (const float*)d_in[16];
  const float* bhh   = (const float*)d_in[17];
  const float* Whsec = (const float*)d_in[18];
  const float* Wdsec = (const float*)d_in[19];
  const float* bdsec = (const float*)d_in[20];
  const float* vsec  = (const float*)d_in[21];
  const float* Whw   = (const float*)d_in[22];
  const float* Wcw   = (const float*)d_in[23];
  const float* Wdw   = (const float*)d_in[24];
  const float* bdw   = (const float*)d_in[25];
  const float* vw    = (const float*)d_in[26];
  const float* Wp    = (const float*)d_in[27];
  const float* bp    = (const float*)d_in[28];
  const float* Wo1   = (const float*)d_in[29];
  const float* bo1   = (const float*)d_in[30];
  const float* Wo2   = (const float*)d_in[31];
  const float* bo2   = (const float*)d_in[32];
  float* out = (float*)d_out;
  float* ws  = (float*)d_ws;
  unsigned short* Btg = (unsigned short*)(ws + OFF_BT);

  k_pre    <<<dim3(81),       dim3(256), 0, stream>>>(Whw, Btg, y, ct1, emb, Wxc, bxc, ws);
  k_lstm   <<<dim3(64),       dim3(256), 0, stream>>>(h0, c0, Wih, bih, Whh, bhh, ws, out);
  k_proj   <<<dim3(128),      dim3(256), 0, stream>>>(Wdsec, bdsec, Wdw, bdw, ws);
  k_gemm6  <<<dim3(928),      dim3(512), 0, stream>>>(enc, Btg, Wcw, vw, cover, sec, Whsec, vsec, ws);
  k_attn   <<<dim3(BB),       dim3(256), 0, stream>>>(mask, cover, ws, out);
  k_ct     <<<dim3(50,BB),    dim3(256), 0, stream>>>(enc, out, ws);
  k_out1   <<<dim3(65),       dim3(256), 0, stream>>>(Wp, bp, Wo1, bo1, ws, out);
  k_logits <<<dim3(NLBLK),    dim3(256), 0, stream>>>(Wo2, bo2, ws, out);
  k_final  <<<dim3(196,BB),   dim3(256), 0, stream>>>(xz, ws, out);
  k_scatter<<<dim3(BB),       dim3(256), 0, stream>>>(ebev, ws, out);
}